// Round 1
// baseline (337.097 us; speedup 1.0000x reference)
//
#include <hip/hip_runtime.h>
#include <hip/hip_bf16.h>

#define BB 8
#define NN 2048
#define DD 128

typedef __attribute__((ext_vector_type(8))) __bf16 bf16x8;
typedef __attribute__((ext_vector_type(4))) float f32x4;
typedef __attribute__((ext_vector_type(4))) int   i32x4;

static __device__ __forceinline__ unsigned short f2bf(float f) {
    union { float f; unsigned u; } v; v.f = f;
    unsigned r = (v.u + 0x7FFFu + ((v.u >> 16) & 1u)) >> 16;
    return (unsigned short)r;
}
static __device__ __forceinline__ float bf2f(unsigned short b) {
    union { unsigned u; float f; } v; v.u = ((unsigned)b) << 16;
    return v.f;
}

// ---------------------------------------------------------------------------
// kernB: per 64-row tile, MFMA GEMMs  si = x@W_self^T + b_self,
// infop = x@W_punct^T ; fused dw = sigmoid(x.w_nw + b_nw) (fp32, accumulated
// during x staging); writes si [n][e] f32, yhat=dw*infop as bf16 in BOTH
// [n][e] (epilogue of kernC) and transposed [e][n] (B-operand of kernC).
// ---------------------------------------------------------------------------
__global__ __launch_bounds__(256) void kernB(
    const float* __restrict__ x,
    const float* __restrict__ w_nw,  const float* __restrict__ b_nw,
    const float* __restrict__ w_self,const float* __restrict__ b_self,
    const float* __restrict__ w_punct,
    float* __restrict__ si_out,
    unsigned short* __restrict__ yne_out,   // [B*N][D] bf16
    unsigned short* __restrict__ yT_out,    // [B][D][N] bf16
    float* __restrict__ aw_out)             // + step*N already applied
{
    __shared__ unsigned short xt[64*32];
    __shared__ unsigned short wst[128*32];
    __shared__ unsigned short wpt[128*32];
    __shared__ float wnw_l[DD];
    __shared__ float red[256];
    __shared__ float dw_l[64];
    __shared__ unsigned short ytl[128*72];  // pad 72 (144B rows, 16B-aligned)

    const int t  = threadIdx.x;
    const int n0 = blockIdx.x * 64;        // global row
    const int b  = n0 >> 11;
    const int nb = n0 & (NN - 1);

    if (t < DD) wnw_l[t] = w_nw[t];
    __syncthreads();

    const int wave = t >> 6, lane = t & 63;
    const int wm = wave >> 1, wn = wave & 1;
    const int quad = lane >> 4, l16 = lane & 15;

    const int n_loc = t >> 2, dq = t & 3;   // x staging role
    const int we = t >> 1,   wh = t & 1;    // W staging role

    f32x4 accs[2][4] = {}; f32x4 accp[2][4] = {};
    float dwpart = 0.f;

    #pragma unroll
    for (int kk = 0; kk < 4; ++kk) {
        const int k0 = kk * 32;
        {   // stage x tile [64 n][32 d] bf16 + dw partial (fp32)
            const float* xs = x + (size_t)(n0 + n_loc) * DD + k0 + dq * 8;
            f32x4 a = *(const f32x4*)xs;
            f32x4 c = *(const f32x4*)(xs + 4);
            const float* wv = &wnw_l[k0 + dq * 8];
            dwpart += a.x*wv[0] + a.y*wv[1] + a.z*wv[2] + a.w*wv[3]
                    + c.x*wv[4] + c.y*wv[5] + c.z*wv[6] + c.w*wv[7];
            unsigned q0 = f2bf(a.x) | ((unsigned)f2bf(a.y) << 16);
            unsigned q1 = f2bf(a.z) | ((unsigned)f2bf(a.w) << 16);
            unsigned q2 = f2bf(c.x) | ((unsigned)f2bf(c.y) << 16);
            unsigned q3 = f2bf(c.z) | ((unsigned)f2bf(c.w) << 16);
            i32x4 pw = {(int)q0,(int)q1,(int)q2,(int)q3};
            *(i32x4*)&xt[n_loc*32 + dq*8] = pw;
        }
        {   // stage W tiles [128 e][32 d] bf16 (both matrices)
            const float* s1 = w_self  + (size_t)we * DD + k0 + wh*16;
            const float* s2 = w_punct + (size_t)we * DD + k0 + wh*16;
            f32x4 a0 = *(const f32x4*)s1;      f32x4 a1 = *(const f32x4*)(s1+4);
            f32x4 a2 = *(const f32x4*)(s1+8);  f32x4 a3 = *(const f32x4*)(s1+12);
            unsigned q0 = f2bf(a0.x) | ((unsigned)f2bf(a0.y)<<16);
            unsigned q1 = f2bf(a0.z) | ((unsigned)f2bf(a0.w)<<16);
            unsigned q2 = f2bf(a1.x) | ((unsigned)f2bf(a1.y)<<16);
            unsigned q3 = f2bf(a1.z) | ((unsigned)f2bf(a1.w)<<16);
            unsigned q4 = f2bf(a2.x) | ((unsigned)f2bf(a2.y)<<16);
            unsigned q5 = f2bf(a2.z) | ((unsigned)f2bf(a2.w)<<16);
            unsigned q6 = f2bf(a3.x) | ((unsigned)f2bf(a3.y)<<16);
            unsigned q7 = f2bf(a3.z) | ((unsigned)f2bf(a3.w)<<16);
            i32x4 pw0 = {(int)q0,(int)q1,(int)q2,(int)q3};
            i32x4 pw1 = {(int)q4,(int)q5,(int)q6,(int)q7};
            *(i32x4*)&wst[we*32 + wh*16]     = pw0;
            *(i32x4*)&wst[we*32 + wh*16 + 8] = pw1;
            f32x4 c0 = *(const f32x4*)s2;      f32x4 c1 = *(const f32x4*)(s2+4);
            f32x4 c2 = *(const f32x4*)(s2+8);  f32x4 c3 = *(const f32x4*)(s2+12);
            unsigned r0 = f2bf(c0.x) | ((unsigned)f2bf(c0.y)<<16);
            unsigned r1 = f2bf(c0.z) | ((unsigned)f2bf(c0.w)<<16);
            unsigned r2 = f2bf(c1.x) | ((unsigned)f2bf(c1.y)<<16);
            unsigned r3 = f2bf(c1.z) | ((unsigned)f2bf(c1.w)<<16);
            unsigned r4 = f2bf(c2.x) | ((unsigned)f2bf(c2.y)<<16);
            unsigned r5 = f2bf(c2.z) | ((unsigned)f2bf(c2.w)<<16);
            unsigned r6 = f2bf(c3.x) | ((unsigned)f2bf(c3.y)<<16);
            unsigned r7 = f2bf(c3.z) | ((unsigned)f2bf(c3.w)<<16);
            i32x4 pv0 = {(int)r0,(int)r1,(int)r2,(int)r3};
            i32x4 pv1 = {(int)r4,(int)r5,(int)r6,(int)r7};
            *(i32x4*)&wpt[we*32 + wh*16]     = pv0;
            *(i32x4*)&wpt[we*32 + wh*16 + 8] = pv1;
        }
        __syncthreads();
        bf16x8 af[2], bs[4], bp[4];
        #pragma unroll
        for (int mt = 0; mt < 2; ++mt)
            af[mt] = *(const bf16x8*)&xt[(wm*32 + mt*16 + l16)*32 + quad*8];
        #pragma unroll
        for (int nt = 0; nt < 4; ++nt) {
            const int er = wn*64 + nt*16 + l16;
            bs[nt] = *(const bf16x8*)&wst[er*32 + quad*8];
            bp[nt] = *(const bf16x8*)&wpt[er*32 + quad*8];
        }
        #pragma unroll
        for (int mt = 0; mt < 2; ++mt)
            #pragma unroll
            for (int nt = 0; nt < 4; ++nt) {
                accs[mt][nt] = __builtin_amdgcn_mfma_f32_16x16x32_bf16(af[mt], bs[nt], accs[mt][nt], 0, 0, 0);
                accp[mt][nt] = __builtin_amdgcn_mfma_f32_16x16x32_bf16(af[mt], bp[nt], accp[mt][nt], 0, 0, 0);
            }
        __syncthreads();
    }

    // dw reduce: 4 partials per row
    red[t] = dwpart;
    __syncthreads();
    if (t < 64) {
        float s = red[4*t] + red[4*t+1] + red[4*t+2] + red[4*t+3] + b_nw[0];
        float dv = 1.f / (1.f + __expf(-s));
        dw_l[t] = dv;
        aw_out[(size_t)b * 2 * NN + nb + t] = dv;
    }
    __syncthreads();

    // epilogue: si, yhat=[n][e], yhat scatter into ytl for transposed writeout
    #pragma unroll
    for (int mt = 0; mt < 2; ++mt) {
        #pragma unroll
        for (int nt = 0; nt < 4; ++nt) {
            const int e = wn*64 + nt*16 + l16;
            const float bsv = b_self[e];
            #pragma unroll
            for (int r = 0; r < 4; ++r) {
                const int nl = wm*32 + mt*16 + quad*4 + r;
                const size_t idx = (size_t)(n0 + nl) * DD + e;
                si_out[idx] = accs[mt][nt][r] + bsv;
                const float yv = dw_l[nl] * accp[mt][nt][r];
                const unsigned short ub = f2bf(yv);
                yne_out[idx] = ub;
                ytl[e*72 + nl] = ub;
            }
        }
    }
    __syncthreads();
    {   // coalesced yT writeout: 128 rows(e) x 64 bf16
        const int e = t >> 1, half = t & 1;
        const i32x4* src = (const i32x4*)&ytl[e*72 + half*32];
        i32x4 v0 = src[0], v1 = src[1], v2 = src[2], v3 = src[3];
        i32x4* dst = (i32x4*)(yT_out + (size_t)(b*DD + e) * NN + nb + half*32);
        dst[0] = v0; dst[1] = v1; dst[2] = v2; dst[3] = v3;
    }
}

// ---------------------------------------------------------------------------
// kernC: agg = Ptilde @ yhat per 64-row tile (Ptilde[i][j]=punct*mask_j,
// converted int32->bf16 during staging; nbr row-sum fused into staging).
// Epilogue: x_new = relu(si + (mask_i/nbr_f)*(acc - punct_ii*yhat_i)).
// ---------------------------------------------------------------------------
__global__ __launch_bounds__(256) void kernC(
    const int* __restrict__ punct, const int* __restrict__ mask,
    const unsigned short* __restrict__ yT,   // [B][D][N] bf16
    const float* __restrict__ si,            // [B*N][D]
    const unsigned short* __restrict__ yne,  // [B*N][D] bf16
    float* __restrict__ x_out)               // [B*N][D]
{
    __shared__ unsigned short pA[64*32];
    __shared__ unsigned short yB[128*32];
    __shared__ int   mask_l[NN];
    __shared__ int   rsum[256];
    __shared__ float scale_l[64];
    __shared__ float pdm_l[64];

    const int t  = threadIdx.x;
    const int b  = blockIdx.x >> 5;
    const int i0 = (blockIdx.x & 31) * 64;
    const size_t rg0 = (size_t)b * NN + i0;

    {   // batch mask -> LDS
        const i32x4* ms = (const i32x4*)(mask + b * NN);
        i32x4* ml = (i32x4*)mask_l;
        ml[t] = ms[t]; ml[t + 256] = ms[t + 256];
    }
    __syncthreads();

    const int wave = t >> 6, lane = t & 63;
    const int wm = wave >> 1, wn = wave & 1;
    const int quad = lane >> 4, l16 = lane & 15;
    const int il = t >> 2, kq = t & 3;   // P staging role
    const int el = t >> 1, kh = t & 1;   // Y staging role

    f32x4 acc[2][4] = {};
    int rs = 0;

    for (int kk = 0; kk < 64; ++kk) {
        const int k0 = kk * 32;
        {   // stage Ptilde = punct & mask_j, + row-sum
            const int* ps = punct + (rg0 + il) * NN + k0 + kq*8;
            i32x4 p0 = *(const i32x4*)ps;
            i32x4 p1 = *(const i32x4*)(ps + 4);
            i32x4 m0 = *(const i32x4*)&mask_l[k0 + kq*8];
            i32x4 m1 = *(const i32x4*)&mask_l[k0 + kq*8 + 4];
            int a0 = p0.x & m0.x, a1 = p0.y & m0.y, a2 = p0.z & m0.z, a3 = p0.w & m0.w;
            int a4 = p1.x & m1.x, a5 = p1.y & m1.y, a6 = p1.z & m1.z, a7 = p1.w & m1.w;
            rs += a0 + a1 + a2 + a3 + a4 + a5 + a6 + a7;
            unsigned w0 = (unsigned)(a0 * 0x3F80) | ((unsigned)(a1 * 0x3F80) << 16);
            unsigned w1 = (unsigned)(a2 * 0x3F80) | ((unsigned)(a3 * 0x3F80) << 16);
            unsigned w2 = (unsigned)(a4 * 0x3F80) | ((unsigned)(a5 * 0x3F80) << 16);
            unsigned w3 = (unsigned)(a6 * 0x3F80) | ((unsigned)(a7 * 0x3F80) << 16);
            i32x4 pw = {(int)w0,(int)w1,(int)w2,(int)w3};
            *(i32x4*)&pA[il*32 + kq*8] = pw;
        }
        {   // stage Y (already transposed [e][j] in ws)
            const unsigned short* ys = yT + (size_t)(b*DD + el) * NN + k0 + kh*16;
            i32x4 v0 = *(const i32x4*)ys;
            i32x4 v1 = *(const i32x4*)(ys + 8);
            i32x4* d = (i32x4*)&yB[el*32 + kh*16];
            d[0] = v0; d[1] = v1;
        }
        __syncthreads();
        bf16x8 af[2], bf[4];
        #pragma unroll
        for (int mt = 0; mt < 2; ++mt)
            af[mt] = *(const bf16x8*)&pA[(wm*32 + mt*16 + l16)*32 + quad*8];
        #pragma unroll
        for (int nt = 0; nt < 4; ++nt)
            bf[nt] = *(const bf16x8*)&yB[(wn*64 + nt*16 + l16)*32 + quad*8];
        #pragma unroll
        for (int mt = 0; mt < 2; ++mt)
            #pragma unroll
            for (int nt = 0; nt < 4; ++nt)
                acc[mt][nt] = __builtin_amdgcn_mfma_f32_16x16x32_bf16(af[mt], bf[nt], acc[mt][nt], 0, 0, 0);
        __syncthreads();
    }

    rsum[t] = rs;
    __syncthreads();
    if (t < 64) {
        int nall = rsum[4*t] + rsum[4*t+1] + rsum[4*t+2] + rsum[4*t+3];
        int mi = mask_l[i0 + t];
        int pd = punct[(rg0 + t) * NN + i0 + t];
        int nbr = mi ? (nall - pd) : 0;          // remove diagonal term
        scale_l[t] = mi ? 1.f / (float)(nbr < 1 ? 1 : nbr) : 0.f;
        pdm_l[t]   = (float)pd;
    }
    __syncthreads();

    #pragma unroll
    for (int mt = 0; mt < 2; ++mt) {
        #pragma unroll
        for (int nt = 0; nt < 4; ++nt) {
            const int e = wn*64 + nt*16 + l16;
            #pragma unroll
            for (int r = 0; r < 4; ++r) {
                const int nl = wm*32 + mt*16 + quad*4 + r;
                const size_t idx = (rg0 + nl) * DD + e;
                const float yv = bf2f(yne[idx]);
                float v = si[idx] + scale_l[nl] * (acc[mt][nt][r] - pdm_l[nl] * yv);
                x_out[idx] = fmaxf(v, 0.f);
            }
        }
    }
}

extern "C" void kernel_launch(void* const* d_in, const int* in_sizes, int n_in,
                              void* d_out, int out_size, void* d_ws, size_t ws_size,
                              hipStream_t stream) {
    const float* node   = (const float*)d_in[0];
    const int*   mask   = (const int*)  d_in[1];
    const int*   punct  = (const int*)  d_in[2];
    const float* w_nw   = (const float*)d_in[3];
    const float* b_nw   = (const float*)d_in[4];
    const float* w_self = (const float*)d_in[5];
    const float* b_self = (const float*)d_in[6];
    const float* w_punct= (const float*)d_in[7];
    // d_in[8] = iteration_steps == 2 (fixed by setup_inputs)

    float* xout = (float*)d_out;
    float* aw   = xout + (size_t)BB * NN * DD;   // all_weight [B][2][N]

    char* w = (char*)d_ws;
    float*          si  = (float*)w;                         // 8 MB
    unsigned short* yne = (unsigned short*)(w + (8u  << 20)); // 4 MB
    unsigned short* yT  = (unsigned short*)(w + (12u << 20)); // 4 MB

    dim3 g(256), blk(256);
    // step 0
    kernB<<<g, blk, 0, stream>>>(node, w_nw, b_nw, w_self, b_self, w_punct,
                                 si, yne, yT, aw /* step 0 */);
    kernC<<<g, blk, 0, stream>>>(punct, mask, yT, si, yne, xout);
    // step 1 (x comes from d_out x-region written by step 0)
    kernB<<<g, blk, 0, stream>>>(xout, w_nw, b_nw, w_self, b_self, w_punct,
                                 si, yne, yT, aw + NN /* step 1 */);
    kernC<<<g, blk, 0, stream>>>(punct, mask, yT, si, yne, xout);
}

// Round 3
// 286.322 us; speedup vs baseline: 1.1773x; 1.1773x over previous
//
#include <hip/hip_runtime.h>
#include <hip/hip_bf16.h>

#define BB 8
#define NN 2048
#define DD 128

typedef __attribute__((ext_vector_type(8))) __bf16 bf16x8;
typedef __attribute__((ext_vector_type(4))) float f32x4;
typedef __attribute__((ext_vector_type(4))) int   i32x4;

static __device__ __forceinline__ unsigned short f2bf(float f) {
    union { float f; unsigned u; } v; v.f = f;
    unsigned r = (v.u + 0x7FFFu + ((v.u >> 16) & 1u)) >> 16;
    return (unsigned short)r;
}
static __device__ __forceinline__ float bf2f(unsigned short b) {
    union { unsigned u; float f; } v; v.u = ((unsigned)b) << 16;
    return v.f;
}

// ---------------------------------------------------------------------------
// kernP (once per call): pack Ptilde[i][j] = punct[i][j] & mask_j into bits
// (64 words per row), and compute scale[i] = mask_i ? 1/max(nbr,1) : 0 and
// pdm[i] = masked diagonal. One wave per row, ballot-packing.
// ---------------------------------------------------------------------------
__global__ __launch_bounds__(256) void kernP(
    const int* __restrict__ punct, const int* __restrict__ mask,
    unsigned* __restrict__ pk, float* __restrict__ scale_g, float* __restrict__ pdm_g)
{
    const int t = threadIdx.x;
    const int wave = t >> 6, lane = t & 63;
    const int row_g = blockIdx.x * 4 + wave;        // 0..16383
    const int b = row_g >> 11;
    const int i = row_g & (NN - 1);

    const int* prow = punct + (size_t)row_g * NN;
    const int* mrow = mask + (size_t)b * NN;

    unsigned pk0 = 0, pk1 = 0;
    int acc = 0;
    #pragma unroll 4
    for (int w = 0; w < 32; ++w) {
        const int col = w * 64 + lane;
        const int p = prow[col];
        const int m = mrow[col];
        const int pred = (p & m) & 1;               // values are {0,1}
        unsigned long long bal = __ballot(pred);
        if (lane == w) { pk0 = (unsigned)bal; pk1 = (unsigned)(bal >> 32); }
        acc += pred + ((col == i ? pred : 0) << 16);
    }
    // wave reduce acc
    #pragma unroll
    for (int o = 32; o > 0; o >>= 1) acc += __shfl_xor(acc, o, 64);

    // lanes 0..31 hold captured ballots for w == lane; lane l stores words
    // 2l, 2l+1 (coalesced 8B/lane). Lanes 32..63 MUST NOT store (round-2 bug:
    // they wrote zeros into the next row's words — race/corruption).
    if (lane < 32) {
        uint2 w2; w2.x = pk0; w2.y = pk1;
        *(uint2*)(pk + (size_t)row_g * 64 + 2 * lane) = w2;
    }

    if (lane == 0) {
        const int nall = acc & 0xFFFF;
        const int pdm  = acc >> 16;                 // masked diagonal (0/1)
        const int mi   = mrow[i];
        const int nbr  = nall - pdm;
        scale_g[row_g] = mi ? 1.f / (float)(nbr < 1 ? 1 : nbr) : 0.f;
        pdm_g[row_g]   = (float)pdm;
    }
}

// ---------------------------------------------------------------------------
// kernB: per 64-row tile, MFMA GEMMs  si = x@W_self^T + b_self,
// infop = x@W_punct^T ; fused dw = sigmoid(x.w_nw + b_nw); writes si [n][e]
// f32, yhat=dw*infop as bf16 in [n][e] and transposed [e][n].
// ---------------------------------------------------------------------------
__global__ __launch_bounds__(256) void kernB(
    const float* __restrict__ x,
    const float* __restrict__ w_nw,  const float* __restrict__ b_nw,
    const float* __restrict__ w_self,const float* __restrict__ b_self,
    const float* __restrict__ w_punct,
    float* __restrict__ si_out,
    unsigned short* __restrict__ yne_out,   // [B*N][D] bf16
    unsigned short* __restrict__ yT_out,    // [B][D][N] bf16
    float* __restrict__ aw_out)             // + step*N already applied
{
    __shared__ unsigned short xt[64*32];
    __shared__ unsigned short wst[128*32];
    __shared__ unsigned short wpt[128*32];
    __shared__ float wnw_l[DD];
    __shared__ float red[256];
    __shared__ float dw_l[64];
    __shared__ unsigned short ytl[128*72];

    const int t  = threadIdx.x;
    const int n0 = blockIdx.x * 64;
    const int b  = n0 >> 11;
    const int nb = n0 & (NN - 1);

    if (t < DD) wnw_l[t] = w_nw[t];
    __syncthreads();

    const int wave = t >> 6, lane = t & 63;
    const int wm = wave >> 1, wn = wave & 1;
    const int quad = lane >> 4, l16 = lane & 15;

    const int n_loc = t >> 2, dq = t & 3;
    const int we = t >> 1,   wh = t & 1;

    f32x4 accs[2][4] = {}; f32x4 accp[2][4] = {};
    float dwpart = 0.f;

    #pragma unroll
    for (int kk = 0; kk < 4; ++kk) {
        const int k0 = kk * 32;
        {
            const float* xs = x + (size_t)(n0 + n_loc) * DD + k0 + dq * 8;
            f32x4 a = *(const f32x4*)xs;
            f32x4 c = *(const f32x4*)(xs + 4);
            const float* wv = &wnw_l[k0 + dq * 8];
            dwpart += a.x*wv[0] + a.y*wv[1] + a.z*wv[2] + a.w*wv[3]
                    + c.x*wv[4] + c.y*wv[5] + c.z*wv[6] + c.w*wv[7];
            unsigned q0 = f2bf(a.x) | ((unsigned)f2bf(a.y) << 16);
            unsigned q1 = f2bf(a.z) | ((unsigned)f2bf(a.w) << 16);
            unsigned q2 = f2bf(c.x) | ((unsigned)f2bf(c.y) << 16);
            unsigned q3 = f2bf(c.z) | ((unsigned)f2bf(c.w) << 16);
            i32x4 pw = {(int)q0,(int)q1,(int)q2,(int)q3};
            *(i32x4*)&xt[n_loc*32 + dq*8] = pw;
        }
        {
            const float* s1 = w_self  + (size_t)we * DD + k0 + wh*16;
            const float* s2 = w_punct + (size_t)we * DD + k0 + wh*16;
            f32x4 a0 = *(const f32x4*)s1;      f32x4 a1 = *(const f32x4*)(s1+4);
            f32x4 a2 = *(const f32x4*)(s1+8);  f32x4 a3 = *(const f32x4*)(s1+12);
            unsigned q0 = f2bf(a0.x) | ((unsigned)f2bf(a0.y)<<16);
            unsigned q1 = f2bf(a0.z) | ((unsigned)f2bf(a0.w)<<16);
            unsigned q2 = f2bf(a1.x) | ((unsigned)f2bf(a1.y)<<16);
            unsigned q3 = f2bf(a1.z) | ((unsigned)f2bf(a1.w)<<16);
            unsigned q4 = f2bf(a2.x) | ((unsigned)f2bf(a2.y)<<16);
            unsigned q5 = f2bf(a2.z) | ((unsigned)f2bf(a2.w)<<16);
            unsigned q6 = f2bf(a3.x) | ((unsigned)f2bf(a3.y)<<16);
            unsigned q7 = f2bf(a3.z) | ((unsigned)f2bf(a3.w)<<16);
            i32x4 pw0 = {(int)q0,(int)q1,(int)q2,(int)q3};
            i32x4 pw1 = {(int)q4,(int)q5,(int)q6,(int)q7};
            *(i32x4*)&wst[we*32 + wh*16]     = pw0;
            *(i32x4*)&wst[we*32 + wh*16 + 8] = pw1;
            f32x4 c0 = *(const f32x4*)s2;      f32x4 c1 = *(const f32x4*)(s2+4);
            f32x4 c2 = *(const f32x4*)(s2+8);  f32x4 c3 = *(const f32x4*)(s2+12);
            unsigned r0 = f2bf(c0.x) | ((unsigned)f2bf(c0.y)<<16);
            unsigned r1 = f2bf(c0.z) | ((unsigned)f2bf(c0.w)<<16);
            unsigned r2 = f2bf(c1.x) | ((unsigned)f2bf(c1.y)<<16);
            unsigned r3 = f2bf(c1.z) | ((unsigned)f2bf(c1.w)<<16);
            unsigned r4 = f2bf(c2.x) | ((unsigned)f2bf(c2.y)<<16);
            unsigned r5 = f2bf(c2.z) | ((unsigned)f2bf(c2.w)<<16);
            unsigned r6 = f2bf(c3.x) | ((unsigned)f2bf(c3.y)<<16);
            unsigned r7 = f2bf(c3.z) | ((unsigned)f2bf(c3.w)<<16);
            i32x4 pv0 = {(int)r0,(int)r1,(int)r2,(int)r3};
            i32x4 pv1 = {(int)r4,(int)r5,(int)r6,(int)r7};
            *(i32x4*)&wpt[we*32 + wh*16]     = pv0;
            *(i32x4*)&wpt[we*32 + wh*16 + 8] = pv1;
        }
        __syncthreads();
        bf16x8 af[2], bs[4], bp[4];
        #pragma unroll
        for (int mt = 0; mt < 2; ++mt)
            af[mt] = *(const bf16x8*)&xt[(wm*32 + mt*16 + l16)*32 + quad*8];
        #pragma unroll
        for (int nt = 0; nt < 4; ++nt) {
            const int er = wn*64 + nt*16 + l16;
            bs[nt] = *(const bf16x8*)&wst[er*32 + quad*8];
            bp[nt] = *(const bf16x8*)&wpt[er*32 + quad*8];
        }
        #pragma unroll
        for (int mt = 0; mt < 2; ++mt)
            #pragma unroll
            for (int nt = 0; nt < 4; ++nt) {
                accs[mt][nt] = __builtin_amdgcn_mfma_f32_16x16x32_bf16(af[mt], bs[nt], accs[mt][nt], 0, 0, 0);
                accp[mt][nt] = __builtin_amdgcn_mfma_f32_16x16x32_bf16(af[mt], bp[nt], accp[mt][nt], 0, 0, 0);
            }
        __syncthreads();
    }

    red[t] = dwpart;
    __syncthreads();
    if (t < 64) {
        float s = red[4*t] + red[4*t+1] + red[4*t+2] + red[4*t+3] + b_nw[0];
        float dv = 1.f / (1.f + __expf(-s));
        dw_l[t] = dv;
        aw_out[(size_t)b * 2 * NN + nb + t] = dv;
    }
    __syncthreads();

    #pragma unroll
    for (int mt = 0; mt < 2; ++mt) {
        #pragma unroll
        for (int nt = 0; nt < 4; ++nt) {
            const int e = wn*64 + nt*16 + l16;
            const float bsv = b_self[e];
            #pragma unroll
            for (int r = 0; r < 4; ++r) {
                const int nl = wm*32 + mt*16 + quad*4 + r;
                const size_t idx = (size_t)(n0 + nl) * DD + e;
                si_out[idx] = accs[mt][nt][r] + bsv;
                const float yv = dw_l[nl] * accp[mt][nt][r];
                const unsigned short ub = f2bf(yv);
                yne_out[idx] = ub;
                ytl[e*72 + nl] = ub;
            }
        }
    }
    __syncthreads();
    {
        const int e = t >> 1, half = t & 1;
        const i32x4* src = (const i32x4*)&ytl[e*72 + half*32];
        i32x4 v0 = src[0], v1 = src[1], v2 = src[2], v3 = src[3];
        i32x4* dst = (i32x4*)(yT_out + (size_t)(b*DD + e) * NN + nb + half*32);
        dst[0] = v0; dst[1] = v1; dst[2] = v2; dst[3] = v3;
    }
}

// ---------------------------------------------------------------------------
// kernC v2: agg = Ptilde @ yhat, Ptilde from packed bits (LDS-resident,
// loaded once), B-fragments loaded direct from L2-resident yT. ZERO barriers
// in the K-loop. Epilogue: x = relu(si + scale*(acc - pdm*yhat_i)).
// ---------------------------------------------------------------------------
__global__ __launch_bounds__(256) void kernC(
    const unsigned* __restrict__ pk,        // [B*N][64] packed bits
    const float* __restrict__ scale_g, const float* __restrict__ pdm_g,
    const unsigned short* __restrict__ yT,  // [B][D][N] bf16
    const float* __restrict__ si,           // [B*N][D]
    const unsigned short* __restrict__ yne, // [B*N][D] bf16
    float* __restrict__ x_out)              // [B*N][D]
{
    __shared__ unsigned pPk[64 * 68];       // 64 rows x 64 words, pad 68
    __shared__ float scale_l[64];
    __shared__ float pdm_l[64];

    const int t  = threadIdx.x;
    const int b  = blockIdx.x >> 5;
    const int i0 = (blockIdx.x & 31) * 64;
    const size_t rg0 = (size_t)b * NN + i0;

    // stage packed bits: 4096 words via 256 thr x 4 x i32x4
    #pragma unroll
    for (int r = 0; r < 4; ++r) {
        const int u   = r * 256 + t;
        const int row = u >> 4;
        const int wq  = (u & 15) * 4;
        i32x4 v = *(const i32x4*)(pk + (rg0 + row) * 64 + wq);
        *(i32x4*)&pPk[row * 68 + wq] = v;
    }
    if (t < 64) {
        scale_l[t] = scale_g[rg0 + t];
        pdm_l[t]   = pdm_g[rg0 + t];
    }
    __syncthreads();

    const int wn = t >> 6, lane = t & 63;
    const int quad = lane >> 4, l16 = lane & 15;
    const unsigned short* yTb = yT + (size_t)b * DD * NN;

    f32x4 acc[4][2] = {};

    #pragma unroll 4
    for (int kk = 0; kk < 64; ++kk) {
        bf16x8 bfr[2];
        #pragma unroll
        for (int nt = 0; nt < 2; ++nt) {
            const int e = wn*32 + nt*16 + l16;
            bfr[nt] = *(const bf16x8*)(yTb + (size_t)e * NN + kk*32 + quad*8);
        }
        bf16x8 af[4];
        #pragma unroll
        for (int mt = 0; mt < 4; ++mt) {
            const unsigned w = pPk[(mt*16 + l16) * 68 + kk];
            const unsigned by = (w >> (quad * 8)) & 0xFFu;
            i32x4 ex;
            ex.x = ((by &   1u) ? 0x3F80 : 0) | ((by &   2u) ? 0x3F800000 : 0);
            ex.y = ((by &   4u) ? 0x3F80 : 0) | ((by &   8u) ? 0x3F800000 : 0);
            ex.z = ((by &  16u) ? 0x3F80 : 0) | ((by &  32u) ? 0x3F800000 : 0);
            ex.w = ((by &  64u) ? 0x3F80 : 0) | ((by & 128u) ? 0x3F800000 : 0);
            union { i32x4 i; bf16x8 h; } cv; cv.i = ex;
            af[mt] = cv.h;
        }
        #pragma unroll
        for (int mt = 0; mt < 4; ++mt)
            #pragma unroll
            for (int nt = 0; nt < 2; ++nt)
                acc[mt][nt] = __builtin_amdgcn_mfma_f32_16x16x32_bf16(af[mt], bfr[nt], acc[mt][nt], 0, 0, 0);
    }

    #pragma unroll
    for (int mt = 0; mt < 4; ++mt) {
        #pragma unroll
        for (int nt = 0; nt < 2; ++nt) {
            const int e = wn*32 + nt*16 + l16;
            #pragma unroll
            for (int r = 0; r < 4; ++r) {
                const int row = mt*16 + quad*4 + r;
                const size_t idx = (rg0 + row) * DD + e;
                const float yv = bf2f(yne[idx]);
                float v = si[idx] + scale_l[row] * (acc[mt][nt][r] - pdm_l[row] * yv);
                x_out[idx] = fmaxf(v, 0.f);
            }
        }
    }
}

extern "C" void kernel_launch(void* const* d_in, const int* in_sizes, int n_in,
                              void* d_out, int out_size, void* d_ws, size_t ws_size,
                              hipStream_t stream) {
    const float* node   = (const float*)d_in[0];
    const int*   mask   = (const int*)  d_in[1];
    const int*   punct  = (const int*)  d_in[2];
    const float* w_nw   = (const float*)d_in[3];
    const float* b_nw   = (const float*)d_in[4];
    const float* w_self = (const float*)d_in[5];
    const float* b_self = (const float*)d_in[6];
    const float* w_punct= (const float*)d_in[7];

    float* xout = (float*)d_out;
    float* aw   = xout + (size_t)BB * NN * DD;

    char* w = (char*)d_ws;
    float*          si   = (float*)w;                          // 8 MB
    unsigned short* yne  = (unsigned short*)(w + (8u  << 20)); // 4 MB
    unsigned short* yT   = (unsigned short*)(w + (12u << 20)); // 4 MB
    unsigned*       pk   = (unsigned*)(w + (16u << 20));       // 4 MB
    float*          scl  = (float*)(w + (20u << 20));          // 64 KB
    float*          pdm  = (float*)(w + (20u << 20) + (64u << 10)); // 64 KB

    dim3 blk(256);
    kernP<<<dim3(4096), blk, 0, stream>>>(punct, mask, pk, scl, pdm);
    // step 0
    kernB<<<dim3(256), blk, 0, stream>>>(node, w_nw, b_nw, w_self, b_self, w_punct,
                                         si, yne, yT, aw);
    kernC<<<dim3(256), blk, 0, stream>>>(pk, scl, pdm, yT, si, yne, xout);
    // step 1
    kernB<<<dim3(256), blk, 0, stream>>>(xout, w_nw, b_nw, w_self, b_self, w_punct,
                                         si, yne, yT, aw + NN);
    kernC<<<dim3(256), blk, 0, stream>>>(pk, scl, pdm, yT, si, yne, xout);
}